// Round 20
// baseline (209.491 us; speedup 1.0000x reference)
//
#include <hip/hip_runtime.h>

#define NN 50000
#define NE 800000
#define INC 128
#define HIDC 64
#define HEADS 4
#define C1 256        // HEADS*HIDC
#define OUTC 32
#define NEG 0.2f
#define EPSV 1e-16f
#define SLOT_CAP 56   // edges-only max degree ~36; P(>=56)~1e-13; guarded anyway
#define CSTRIDE 16    // curs padded: one counter per 64B line

// block partition constants
#define NB_CASTX 3125        // 800000/256
#define NB_ZERO  3125        // 800000 padded curs ints / 256
#define NB_W1T   128
#define NB_W2T   32
#define NB_PREP  (NB_CASTX + NB_ZERO + NB_W1T + NB_W2T)
#define EB2      3125        // ceil(NE/256)
#define NB_G1S   782         // ceil(NN/64) — single row pass, 4 heads in-loop
#define NB_GS    (EB2 + NB_G1S)

// workspace element offsets (4-byte units)
#define CURS  0          // [800000] i (padded, zeroed in prep) -> 800000
#define ASRC1 800000     // [200000] f -> 1000000
#define ADST1 1000000    // [200000] f -> 1200000
#define ASRC2 1200000    // [50000]  f -> 1250000
#define ADST2 1250000    // [50000]  f -> 1300000
#define SLOTS 1300000    // [2800000] i (50000x56) -> 4100000
#define W1T   4100000    // 32768 bf16 = 16384 f -> 4116384
#define W2T   4116384    // 8192 bf16 = 4096 f -> 4120480
#define XBF   4120480    // 6400000 bf16 = 3200000 f -> 7320480
#define H1B   7320480    // 12800000 bf16 = 6400000 f -> 13720480
#define H2B   13720480   // 12800000 bf16 = 6400000 f -> 20120480
#define H3OFF 20120480   // 1600000 bf16 = 800000 f -> 20920480
#define WS_NEED_FLOATS 20920480ull

typedef __attribute__((ext_vector_type(8))) short short8v;
typedef __attribute__((ext_vector_type(4))) float floatx4;

__device__ __forceinline__ unsigned short f2bf(float f) {
    unsigned u = __float_as_uint(f);
    unsigned r = (u + 0x7fffu + ((u >> 16) & 1u)) >> 16;
    return (unsigned short)r;
}
__device__ __forceinline__ float bf2f(unsigned short s) {
    return __uint_as_float(((unsigned)s) << 16);
}
__device__ __forceinline__ float lrelu(float v) { return v >= 0.f ? v : NEG * v; }

// ---- fused prep: cast_x | zero padded curs | cast W1T | cast W2T ----
__global__ __launch_bounds__(256) void prep(const float* __restrict__ x,
                                            const float* __restrict__ W1,
                                            const float* __restrict__ W2,
                                            unsigned short* __restrict__ xbf,
                                            unsigned short* __restrict__ w1t,
                                            unsigned short* __restrict__ w2t,
                                            int* __restrict__ curs) {
    const int bid = blockIdx.x, tid = threadIdx.x;
    if (bid < NB_CASTX) {
        int i = bid * 256 + tid;                 // exactly 800000 threads
        float4 v0 = ((const float4*)x)[i * 2];
        float4 v1 = ((const float4*)x)[i * 2 + 1];
        short8v o;
        o[0] = (short)f2bf(v0.x); o[1] = (short)f2bf(v0.y);
        o[2] = (short)f2bf(v0.z); o[3] = (short)f2bf(v0.w);
        o[4] = (short)f2bf(v1.x); o[5] = (short)f2bf(v1.y);
        o[6] = (short)f2bf(v1.z); o[7] = (short)f2bf(v1.w);
        *(short8v*)(xbf + (size_t)i * 8) = o;
    } else if (bid < NB_CASTX + NB_ZERO) {
        int i = (bid - NB_CASTX) * 256 + tid;    // exactly 800000 ints
        curs[i] = 0;
    } else if (bid < NB_CASTX + NB_ZERO + NB_W1T) {
        int i = (bid - NB_CASTX - NB_ZERO) * 256 + tid;   // exactly 32768
        int n = i >> 7, k = i & 127;
        w1t[(size_t)n * INC + k] = f2bf(W1[(size_t)k * C1 + n]);
    } else {
        int i = (bid - NB_CASTX - NB_ZERO - NB_W1T) * 256 + tid;  // exactly 8192
        int n = i >> 8, k = i & 255;
        w2t[(size_t)n * C1 + k] = f2bf(W2[(size_t)k * OUTC + n]);
    }
}

// ---- fused: edge slot-scatter | gemm1 single row-pass over 4 heads (no LDS) ----
__global__ __launch_bounds__(256) void gemm1_scatter(const unsigned short* __restrict__ xbf,
                                                     const unsigned short* __restrict__ w1t,
                                                     const float* __restrict__ att_src,
                                                     const float* __restrict__ att_dst,
                                                     const int* __restrict__ ei,
                                                     unsigned short* __restrict__ h1b,
                                                     float* __restrict__ a_src,
                                                     float* __restrict__ a_dst,
                                                     int* __restrict__ curs,
                                                     int* __restrict__ slots) {
    const int bid = blockIdx.x;
    if (bid < EB2) {
        int e = bid * 256 + threadIdx.x;
        if (e < NE) {
            int s = ei[e], d = ei[NE + e];
            int pos = atomicAdd(&curs[d * CSTRIDE], 1);
            if (pos < SLOT_CAP) slots[(size_t)d * SLOT_CAP + pos] = s;
        }
        return;
    }
    const int b2 = bid - EB2;                    // 0..781
    const int tid = threadIdx.x;
    const int w = tid >> 6, lane = tid & 63;
    const int l15 = lane & 15, kg = lane >> 4;
    const int mb = b2 * 64 + w * 16;
    int ar = mb + l15; if (ar >= NN) ar = NN - 1;

    short8v a[4];
    #pragma unroll
    for (int ks = 0; ks < 4; ++ks)
        a[ks] = *(const short8v*)(xbf + (size_t)ar * INC + ks * 32 + kg * 8);

    #pragma unroll
    for (int hh = 0; hh < 4; ++hh) {
        const int nb = hh * 64;
        short8v b[4][4];
        #pragma unroll
        for (int nt = 0; nt < 4; ++nt) {
            int nc = nb + nt * 16 + l15;
            #pragma unroll
            for (int ks = 0; ks < 4; ++ks)
                b[ks][nt] = *(const short8v*)(w1t + (size_t)nc * INC + ks * 32 + kg * 8);
        }
        floatx4 acc[4] = {{0.f,0.f,0.f,0.f},{0.f,0.f,0.f,0.f},{0.f,0.f,0.f,0.f},{0.f,0.f,0.f,0.f}};
        #pragma unroll
        for (int ks = 0; ks < 4; ++ks)
            #pragma unroll
            for (int nt = 0; nt < 4; ++nt)
                acc[nt] = __builtin_amdgcn_mfma_f32_16x16x32_bf16(a[ks], b[ks][nt], acc[nt], 0, 0, 0);

        // direct h1 store (round-18 pattern, bitwise identical values)
        #pragma unroll
        for (int nt = 0; nt < 4; ++nt)
            #pragma unroll
            for (int j = 0; j < 4; ++j) {
                int r = mb + kg * 4 + j;
                if (r < NN) h1b[(size_t)r * C1 + nb + nt * 16 + l15] = f2bf(acc[nt][j]);
            }

        // fused attention dots for head hh
        float ws_[4], wd_[4];
        #pragma unroll
        for (int nt = 0; nt < 4; ++nt) {
            ws_[nt] = att_src[nb + nt * 16 + l15];
            wd_[nt] = att_dst[nb + nt * 16 + l15];
        }
        #pragma unroll
        for (int j = 0; j < 4; ++j) {
            float ps = acc[0][j] * ws_[0] + acc[1][j] * ws_[1] + acc[2][j] * ws_[2] + acc[3][j] * ws_[3];
            float pd = acc[0][j] * wd_[0] + acc[1][j] * wd_[1] + acc[2][j] * wd_[2] + acc[3][j] * wd_[3];
            #pragma unroll
            for (int m = 8; m; m >>= 1) {
                ps += __shfl_xor(ps, m);
                pd += __shfl_xor(pd, m);
            }
            int r = mb + kg * 4 + j;
            if (l15 == 0 && r < NN) {
                a_src[r * 4 + hh] = ps;
                a_dst[r * 4 + hh] = pd;
            }
        }
    }
}

// layer-1 aggregation, 8x unrolled gather; analytic self-loop; padded curs
__global__ __launch_bounds__(256) void node1(const unsigned short* __restrict__ h1b,
                                             const int* __restrict__ curs,
                                             const int* __restrict__ slots,
                                             const float* __restrict__ a_src,
                                             const float* __restrict__ a_dst,
                                             const float* __restrict__ b1,
                                             unsigned short* __restrict__ h2b) {
    int wave = threadIdx.x >> 6, lane = threadIdx.x & 63;
    int n = blockIdx.x * 4 + wave;
    if (n >= NN) return;
    int h = lane >> 4;
    int cnt = curs[n * CSTRIDE]; if (cnt > SLOT_CAP) cnt = SLOT_CAP;
    const int* sl = slots + (size_t)n * SLOT_CAP;
    float adh = a_dst[n * 4 + h];
    float a0 = 0.f, a1 = 0.f, a2 = 0.f, a3 = 0.f, den = 0.f;
    {   // self-loop
        float e = __expf(lrelu(a_src[n * 4 + h] + adh));
        den += e;
        uint2 rv = *(const uint2*)(h1b + (size_t)n * C1 + lane * 4);
        a0 += bf2f((unsigned short)(rv.x & 0xffff)) * e;
        a1 += bf2f((unsigned short)(rv.x >> 16)) * e;
        a2 += bf2f((unsigned short)(rv.y & 0xffff)) * e;
        a3 += bf2f((unsigned short)(rv.y >> 16)) * e;
    }
    int p = 0;
    for (; p + 7 < cnt; p += 8) {
        int sA[8];
        #pragma unroll
        for (int j = 0; j < 8; ++j) sA[j] = sl[p + j];
        uint2 rA[8];
        #pragma unroll
        for (int j = 0; j < 8; ++j) rA[j] = *(const uint2*)(h1b + (size_t)sA[j] * C1 + lane * 4);
        float eA[8];
        #pragma unroll
        for (int j = 0; j < 8; ++j) eA[j] = __expf(lrelu(a_src[sA[j] * 4 + h] + adh));
        #pragma unroll
        for (int j = 0; j < 8; ++j) {
            den += eA[j];
            a0 += bf2f((unsigned short)(rA[j].x & 0xffff)) * eA[j];
            a1 += bf2f((unsigned short)(rA[j].x >> 16)) * eA[j];
            a2 += bf2f((unsigned short)(rA[j].y & 0xffff)) * eA[j];
            a3 += bf2f((unsigned short)(rA[j].y >> 16)) * eA[j];
        }
    }
    for (; p + 3 < cnt; p += 4) {
        int sA[4];
        #pragma unroll
        for (int j = 0; j < 4; ++j) sA[j] = sl[p + j];
        uint2 rA[4];
        #pragma unroll
        for (int j = 0; j < 4; ++j) rA[j] = *(const uint2*)(h1b + (size_t)sA[j] * C1 + lane * 4);
        float eA[4];
        #pragma unroll
        for (int j = 0; j < 4; ++j) eA[j] = __expf(lrelu(a_src[sA[j] * 4 + h] + adh));
        #pragma unroll
        for (int j = 0; j < 4; ++j) {
            den += eA[j];
            a0 += bf2f((unsigned short)(rA[j].x & 0xffff)) * eA[j];
            a1 += bf2f((unsigned short)(rA[j].x >> 16)) * eA[j];
            a2 += bf2f((unsigned short)(rA[j].y & 0xffff)) * eA[j];
            a3 += bf2f((unsigned short)(rA[j].y >> 16)) * eA[j];
        }
    }
    for (; p < cnt; ++p) {
        int s = sl[p];
        float e = __expf(lrelu(a_src[s * 4 + h] + adh));
        den += e;
        uint2 rv = *(const uint2*)(h1b + (size_t)s * C1 + lane * 4);
        a0 += bf2f((unsigned short)(rv.x & 0xffff)) * e;
        a1 += bf2f((unsigned short)(rv.x >> 16)) * e;
        a2 += bf2f((unsigned short)(rv.y & 0xffff)) * e;
        a3 += bf2f((unsigned short)(rv.y >> 16)) * e;
    }
    float inv = 1.f / (den + EPSV);
    float4 bb = *(const float4*)(b1 + lane * 4);
    float o0 = a0 * inv + bb.x;
    float o1 = a1 * inv + bb.y;
    float o2 = a2 * inv + bb.z;
    float o3 = a3 * inv + bb.w;
    o0 = o0 > 0.f ? o0 : __expf(o0) - 1.f;
    o1 = o1 > 0.f ? o1 : __expf(o1) - 1.f;
    o2 = o2 > 0.f ? o2 : __expf(o2) - 1.f;
    o3 = o3 > 0.f ? o3 : __expf(o3) - 1.f;
    uint2 ov;
    ov.x = (unsigned)f2bf(o0) | ((unsigned)f2bf(o1) << 16);
    ov.y = (unsigned)f2bf(o2) | ((unsigned)f2bf(o3) << 16);
    *(uint2*)(h2b + (size_t)n * C1 + lane * 4) = ov;
}

// h3 = h2 @ W2 via MFMA bf16; h3 stored bf16; fused layer-2 attention dots
__global__ __launch_bounds__(256) void gemm2_mfma(const unsigned short* __restrict__ h2b,
                                                  const unsigned short* __restrict__ w2t,
                                                  const float* __restrict__ att_src,
                                                  const float* __restrict__ att_dst,
                                                  unsigned short* __restrict__ h3b,
                                                  float* __restrict__ a_src,
                                                  float* __restrict__ a_dst) {
    const int tid = threadIdx.x;
    const int w = tid >> 6, lane = tid & 63;
    const int l15 = lane & 15, kg = lane >> 4;
    const int mb = blockIdx.x * 64 + w * 16;
    int ar = mb + l15; if (ar >= NN) ar = NN - 1;

    short8v a[8];
    #pragma unroll
    for (int ks = 0; ks < 8; ++ks)
        a[ks] = *(const short8v*)(h2b + (size_t)ar * C1 + ks * 32 + kg * 8);

    short8v b[8][2];
    #pragma unroll
    for (int nt = 0; nt < 2; ++nt) {
        int nc = nt * 16 + l15;
        #pragma unroll
        for (int ks = 0; ks < 8; ++ks)
            b[ks][nt] = *(const short8v*)(w2t + (size_t)nc * C1 + ks * 32 + kg * 8);
    }

    floatx4 acc[2] = {{0.f,0.f,0.f,0.f},{0.f,0.f,0.f,0.f}};
    #pragma unroll
    for (int ks = 0; ks < 8; ++ks)
        #pragma unroll
        for (int nt = 0; nt < 2; ++nt)
            acc[nt] = __builtin_amdgcn_mfma_f32_16x16x32_bf16(a[ks], b[ks][nt], acc[nt], 0, 0, 0);

    #pragma unroll
    for (int nt = 0; nt < 2; ++nt)
        #pragma unroll
        for (int j = 0; j < 4; ++j) {
            int r = mb + kg * 4 + j;
            if (r < NN) h3b[(size_t)r * OUTC + nt * 16 + l15] = f2bf(acc[nt][j]);
        }

    float ws0 = att_src[l15], ws1 = att_src[16 + l15];
    float wd0 = att_dst[l15], wd1 = att_dst[16 + l15];
    #pragma unroll
    for (int j = 0; j < 4; ++j) {
        float ps = acc[0][j] * ws0 + acc[1][j] * ws1;
        float pd = acc[0][j] * wd0 + acc[1][j] * wd1;
        #pragma unroll
        for (int m = 8; m; m >>= 1) {
            ps += __shfl_xor(ps, m);
            pd += __shfl_xor(pd, m);
        }
        int r = mb + kg * 4 + j;
        if (l15 == 0 && r < NN) {
            a_src[r] = ps;
            a_dst[r] = pd;
        }
    }
}

// layer-2 aggregation, 4x unrolled, slot CSR (bf16 h3); analytic self-loop; padded curs
__global__ __launch_bounds__(256) void node2(const unsigned short* __restrict__ h3b,
                                             const int* __restrict__ curs,
                                             const int* __restrict__ slots,
                                             const float* __restrict__ a_src,
                                             const float* __restrict__ a_dst,
                                             const float* __restrict__ b2,
                                             float* __restrict__ out) {
    int wave = threadIdx.x >> 6, lane = threadIdx.x & 63;
    int half = lane >> 5, c = lane & 31;
    int n = blockIdx.x * 8 + wave * 2 + half;
    if (n >= NN) return;
    int cnt = curs[n * CSTRIDE]; if (cnt > SLOT_CAP) cnt = SLOT_CAP;
    const int* sl = slots + (size_t)n * SLOT_CAP;
    float adn = a_dst[n];
    float acc = 0.f, den = 0.f;
    {   // self-loop
        float e = __expf(lrelu(a_src[n] + adn));
        den += e;
        acc += bf2f(h3b[(size_t)n * OUTC + c]) * e;
    }
    int p = 0;
    for (; p + 3 < cnt; p += 4) {
        int s0 = sl[p], s1 = sl[p + 1], s2 = sl[p + 2], s3 = sl[p + 3];
        float g0 = bf2f(h3b[(size_t)s0 * OUTC + c]);
        float g1 = bf2f(h3b[(size_t)s1 * OUTC + c]);
        float g2 = bf2f(h3b[(size_t)s2 * OUTC + c]);
        float g3 = bf2f(h3b[(size_t)s3 * OUTC + c]);
        float e0 = __expf(lrelu(a_src[s0] + adn));
        float e1 = __expf(lrelu(a_src[s1] + adn));
        float e2 = __expf(lrelu(a_src[s2] + adn));
        float e3 = __expf(lrelu(a_src[s3] + adn));
        den += e0 + e1 + e2 + e3;
        acc += g0 * e0 + g1 * e1 + g2 * e2 + g3 * e3;
    }
    for (; p < cnt; ++p) {
        int s = sl[p];
        float e = __expf(lrelu(a_src[s] + adn));
        den += e;
        acc += bf2f(h3b[(size_t)s * OUTC + c]) * e;
    }
    out[(size_t)n * OUTC + c] = acc / (den + EPSV) + b2[c];
}

extern "C" void kernel_launch(void* const* d_in, const int* in_sizes, int n_in,
                              void* d_out, int out_size, void* d_ws, size_t ws_size,
                              hipStream_t stream) {
    if (ws_size < WS_NEED_FLOATS * 4ull) return;

    const float* x        = (const float*)d_in[0];
    const int* ei         = (const int*)d_in[1];
    const float* W1       = (const float*)d_in[2];
    const float* att_src1 = (const float*)d_in[3];
    const float* att_dst1 = (const float*)d_in[4];
    const float* b1       = (const float*)d_in[5];
    const float* W2       = (const float*)d_in[6];
    const float* att_src2 = (const float*)d_in[7];
    const float* att_dst2 = (const float*)d_in[8];
    const float* b2       = (const float*)d_in[9];
    float* out = (float*)d_out;
    float* ws  = (float*)d_ws;
    int*   wsi = (int*)d_ws;

    int*   curs   = wsi + CURS;
    float* a_src1 = ws + ASRC1;
    float* a_dst1 = ws + ADST1;
    float* a_src2 = ws + ASRC2;
    float* a_dst2 = ws + ADST2;
    int*   slots  = wsi + SLOTS;
    unsigned short* w1t = (unsigned short*)(ws + W1T);
    unsigned short* w2t = (unsigned short*)(ws + W2T);
    unsigned short* xbf = (unsigned short*)(ws + XBF);
    unsigned short* h1b = (unsigned short*)(ws + H1B);
    unsigned short* h2b = (unsigned short*)(ws + H2B);
    unsigned short* h3b = (unsigned short*)(ws + H3OFF);

    hipLaunchKernelGGL(prep, dim3(NB_PREP), dim3(256), 0, stream,
                       x, W1, W2, xbf, w1t, w2t, curs);
    hipLaunchKernelGGL(gemm1_scatter, dim3(NB_GS), dim3(256), 0, stream,
                       xbf, w1t, att_src1, att_dst1, ei, h1b, a_src1, a_dst1, curs, slots);
    hipLaunchKernelGGL(node1, dim3((NN + 3) / 4), dim3(256), 0, stream,
                       h1b, curs, slots, a_src1, a_dst1, b1, h2b);
    hipLaunchKernelGGL(gemm2_mfma, dim3((NN + 63) / 64), dim3(256), 0, stream,
                       h2b, w2t, att_src2, att_dst2, h3b, a_src2, a_dst2);
    hipLaunchKernelGGL(node2, dim3((NN + 7) / 8), dim3(256), 0, stream,
                       h3b, curs, slots, a_src2, a_dst2, b2, out);
}

// Round 21
// 189.585 us; speedup vs baseline: 1.1050x; 1.1050x over previous
//
#include <hip/hip_runtime.h>

#define NN 50000
#define NE 800000
#define INC 128
#define HIDC 64
#define HEADS 4
#define C1 256        // HEADS*HIDC
#define OUTC 32
#define NEG 0.2f
#define EPSV 1e-16f
#define SLOT_CAP 56   // edges-only max degree ~36; P(>=56)~1e-13; guarded anyway
#define CSTRIDE 16    // curs padded: one counter per 64B line

// block partition constants
#define NB_CASTX 3125        // 800000/256
#define NB_ZERO  3125        // 800000 padded curs ints / 256
#define NB_W1T   128
#define NB_W2T   32
#define NB_PREP  (NB_CASTX + NB_ZERO + NB_W1T + NB_W2T)
#define EB2      3125        // ceil(NE/256)
#define NB_G1S   782         // ceil(NN/64)
#define NB_G1    (NB_G1S * 4)
#define NB_GS    (EB2 + NB_G1)   // fused scatter | gemm1 (4-head grid)

// workspace element offsets (4-byte units)
#define CURS  0          // [800000] i (padded, zeroed in prep) -> 800000
#define ASRC1 800000     // [200000] f -> 1000000
#define ADST1 1000000    // [200000] f -> 1200000
#define ASRC2 1200000    // [50000]  f -> 1250000
#define ADST2 1250000    // [50000]  f -> 1300000
#define SLOTS 1300000    // [2800000] i (50000x56) -> 4100000
#define W1T   4100000    // 32768 bf16 = 16384 f -> 4116384
#define W2T   4116384    // 8192 bf16 = 4096 f -> 4120480
#define XBF   4120480    // 6400000 bf16 = 3200000 f -> 7320480
#define H1B   7320480    // 12800000 bf16 = 6400000 f -> 13720480
#define H2B   13720480   // 12800000 bf16 = 6400000 f -> 20120480
#define H3OFF 20120480   // 1600000 bf16 = 800000 f -> 20920480
#define WS_NEED_FLOATS 20920480ull

typedef __attribute__((ext_vector_type(8))) short short8v;
typedef __attribute__((ext_vector_type(4))) float floatx4;

__device__ __forceinline__ unsigned short f2bf(float f) {
    unsigned u = __float_as_uint(f);
    unsigned r = (u + 0x7fffu + ((u >> 16) & 1u)) >> 16;
    return (unsigned short)r;
}
__device__ __forceinline__ float bf2f(unsigned short s) {
    return __uint_as_float(((unsigned)s) << 16);
}
__device__ __forceinline__ float lrelu(float v) { return v >= 0.f ? v : NEG * v; }

// ---- fused prep: cast_x | zero padded curs | cast W1T | cast W2T ----
__global__ __launch_bounds__(256) void prep(const float* __restrict__ x,
                                            const float* __restrict__ W1,
                                            const float* __restrict__ W2,
                                            unsigned short* __restrict__ xbf,
                                            unsigned short* __restrict__ w1t,
                                            unsigned short* __restrict__ w2t,
                                            int* __restrict__ curs) {
    const int bid = blockIdx.x, tid = threadIdx.x;
    if (bid < NB_CASTX) {
        int i = bid * 256 + tid;                 // exactly 800000 threads
        float4 v0 = ((const float4*)x)[i * 2];
        float4 v1 = ((const float4*)x)[i * 2 + 1];
        short8v o;
        o[0] = (short)f2bf(v0.x); o[1] = (short)f2bf(v0.y);
        o[2] = (short)f2bf(v0.z); o[3] = (short)f2bf(v0.w);
        o[4] = (short)f2bf(v1.x); o[5] = (short)f2bf(v1.y);
        o[6] = (short)f2bf(v1.z); o[7] = (short)f2bf(v1.w);
        *(short8v*)(xbf + (size_t)i * 8) = o;
    } else if (bid < NB_CASTX + NB_ZERO) {
        int i = (bid - NB_CASTX) * 256 + tid;    // exactly 800000 ints
        curs[i] = 0;
    } else if (bid < NB_CASTX + NB_ZERO + NB_W1T) {
        int i = (bid - NB_CASTX - NB_ZERO) * 256 + tid;   // exactly 32768
        int n = i >> 7, k = i & 127;
        w1t[(size_t)n * INC + k] = f2bf(W1[(size_t)k * C1 + n]);
    } else {
        int i = (bid - NB_CASTX - NB_ZERO - NB_W1T) * 256 + tid;  // exactly 8192
        int n = i >> 8, k = i & 255;
        w2t[(size_t)n * C1 + k] = f2bf(W2[(size_t)k * OUTC + n]);
    }
}

// ---- fused: edge slot-scatter (padded curs) | gemm1 MFMA + attdots (4-head grid) ----
__global__ __launch_bounds__(256) void gemm1_scatter(const unsigned short* __restrict__ xbf,
                                                     const unsigned short* __restrict__ w1t,
                                                     const float* __restrict__ att_src,
                                                     const float* __restrict__ att_dst,
                                                     const int* __restrict__ ei,
                                                     unsigned short* __restrict__ h1b,
                                                     float* __restrict__ a_src,
                                                     float* __restrict__ a_dst,
                                                     int* __restrict__ curs,
                                                     int* __restrict__ slots) {
    const int bid = blockIdx.x;
    if (bid < EB2) {
        int e = bid * 256 + threadIdx.x;
        if (e < NE) {
            int s = ei[e], d = ei[NE + e];
            int pos = atomicAdd(&curs[d * CSTRIDE], 1);
            if (pos < SLOT_CAP) slots[(size_t)d * SLOT_CAP + pos] = s;
        }
        return;
    }
    const int b2 = bid - EB2;
    const int strip = b2 % NB_G1S;
    const int by = b2 / NB_G1S;         // head
    const int tid = threadIdx.x;
    const int w = tid >> 6, lane = tid & 63;
    const int l15 = lane & 15, kg = lane >> 4;
    const int mb = strip * 64 + w * 16;
    const int nb = by * 64;
    int ar = mb + l15; if (ar >= NN) ar = NN - 1;

    short8v a[4];
    #pragma unroll
    for (int ks = 0; ks < 4; ++ks)
        a[ks] = *(const short8v*)(xbf + (size_t)ar * INC + ks * 32 + kg * 8);

    short8v b[4][4];
    #pragma unroll
    for (int nt = 0; nt < 4; ++nt) {
        int nc = nb + nt * 16 + l15;
        #pragma unroll
        for (int ks = 0; ks < 4; ++ks)
            b[ks][nt] = *(const short8v*)(w1t + (size_t)nc * INC + ks * 32 + kg * 8);
    }

    floatx4 acc[4] = {{0.f,0.f,0.f,0.f},{0.f,0.f,0.f,0.f},{0.f,0.f,0.f,0.f},{0.f,0.f,0.f,0.f}};
    #pragma unroll
    for (int ks = 0; ks < 4; ++ks)
        #pragma unroll
        for (int nt = 0; nt < 4; ++nt)
            acc[nt] = __builtin_amdgcn_mfma_f32_16x16x32_bf16(a[ks], b[ks][nt], acc[nt], 0, 0, 0);

    #pragma unroll
    for (int nt = 0; nt < 4; ++nt)
        #pragma unroll
        for (int j = 0; j < 4; ++j) {
            int r = mb + kg * 4 + j;
            if (r < NN) h1b[(size_t)r * C1 + nb + nt * 16 + l15] = f2bf(acc[nt][j]);
        }

    float ws_[4], wd_[4];
    #pragma unroll
    for (int nt = 0; nt < 4; ++nt) {
        ws_[nt] = att_src[nb + nt * 16 + l15];
        wd_[nt] = att_dst[nb + nt * 16 + l15];
    }
    #pragma unroll
    for (int j = 0; j < 4; ++j) {
        float ps = acc[0][j] * ws_[0] + acc[1][j] * ws_[1] + acc[2][j] * ws_[2] + acc[3][j] * ws_[3];
        float pd = acc[0][j] * wd_[0] + acc[1][j] * wd_[1] + acc[2][j] * wd_[2] + acc[3][j] * wd_[3];
        #pragma unroll
        for (int m = 8; m; m >>= 1) {
            ps += __shfl_xor(ps, m);
            pd += __shfl_xor(pd, m);
        }
        int r = mb + kg * 4 + j;
        if (l15 == 0 && r < NN) {
            a_src[r * 4 + by] = ps;
            a_dst[r * 4 + by] = pd;
        }
    }
}

// layer-1 aggregation, 8x unrolled gather; analytic self-loop; padded curs
__global__ __launch_bounds__(256) void node1(const unsigned short* __restrict__ h1b,
                                             const int* __restrict__ curs,
                                             const int* __restrict__ slots,
                                             const float* __restrict__ a_src,
                                             const float* __restrict__ a_dst,
                                             const float* __restrict__ b1,
                                             unsigned short* __restrict__ h2b) {
    int wave = threadIdx.x >> 6, lane = threadIdx.x & 63;
    int n = blockIdx.x * 4 + wave;
    if (n >= NN) return;
    int h = lane >> 4;
    int cnt = curs[n * CSTRIDE]; if (cnt > SLOT_CAP) cnt = SLOT_CAP;
    const int* sl = slots + (size_t)n * SLOT_CAP;
    float adh = a_dst[n * 4 + h];
    float a0 = 0.f, a1 = 0.f, a2 = 0.f, a3 = 0.f, den = 0.f;
    {   // self-loop
        float e = __expf(lrelu(a_src[n * 4 + h] + adh));
        den += e;
        uint2 rv = *(const uint2*)(h1b + (size_t)n * C1 + lane * 4);
        a0 += bf2f((unsigned short)(rv.x & 0xffff)) * e;
        a1 += bf2f((unsigned short)(rv.x >> 16)) * e;
        a2 += bf2f((unsigned short)(rv.y & 0xffff)) * e;
        a3 += bf2f((unsigned short)(rv.y >> 16)) * e;
    }
    int p = 0;
    for (; p + 7 < cnt; p += 8) {
        int sA[8];
        #pragma unroll
        for (int j = 0; j < 8; ++j) sA[j] = sl[p + j];
        uint2 rA[8];
        #pragma unroll
        for (int j = 0; j < 8; ++j) rA[j] = *(const uint2*)(h1b + (size_t)sA[j] * C1 + lane * 4);
        float eA[8];
        #pragma unroll
        for (int j = 0; j < 8; ++j) eA[j] = __expf(lrelu(a_src[sA[j] * 4 + h] + adh));
        #pragma unroll
        for (int j = 0; j < 8; ++j) {
            den += eA[j];
            a0 += bf2f((unsigned short)(rA[j].x & 0xffff)) * eA[j];
            a1 += bf2f((unsigned short)(rA[j].x >> 16)) * eA[j];
            a2 += bf2f((unsigned short)(rA[j].y & 0xffff)) * eA[j];
            a3 += bf2f((unsigned short)(rA[j].y >> 16)) * eA[j];
        }
    }
    for (; p + 3 < cnt; p += 4) {
        int sA[4];
        #pragma unroll
        for (int j = 0; j < 4; ++j) sA[j] = sl[p + j];
        uint2 rA[4];
        #pragma unroll
        for (int j = 0; j < 4; ++j) rA[j] = *(const uint2*)(h1b + (size_t)sA[j] * C1 + lane * 4);
        float eA[4];
        #pragma unroll
        for (int j = 0; j < 4; ++j) eA[j] = __expf(lrelu(a_src[sA[j] * 4 + h] + adh));
        #pragma unroll
        for (int j = 0; j < 4; ++j) {
            den += eA[j];
            a0 += bf2f((unsigned short)(rA[j].x & 0xffff)) * eA[j];
            a1 += bf2f((unsigned short)(rA[j].x >> 16)) * eA[j];
            a2 += bf2f((unsigned short)(rA[j].y & 0xffff)) * eA[j];
            a3 += bf2f((unsigned short)(rA[j].y >> 16)) * eA[j];
        }
    }
    for (; p < cnt; ++p) {
        int s = sl[p];
        float e = __expf(lrelu(a_src[s * 4 + h] + adh));
        den += e;
        uint2 rv = *(const uint2*)(h1b + (size_t)s * C1 + lane * 4);
        a0 += bf2f((unsigned short)(rv.x & 0xffff)) * e;
        a1 += bf2f((unsigned short)(rv.x >> 16)) * e;
        a2 += bf2f((unsigned short)(rv.y & 0xffff)) * e;
        a3 += bf2f((unsigned short)(rv.y >> 16)) * e;
    }
    float inv = 1.f / (den + EPSV);
    float4 bb = *(const float4*)(b1 + lane * 4);
    float o0 = a0 * inv + bb.x;
    float o1 = a1 * inv + bb.y;
    float o2 = a2 * inv + bb.z;
    float o3 = a3 * inv + bb.w;
    o0 = o0 > 0.f ? o0 : __expf(o0) - 1.f;
    o1 = o1 > 0.f ? o1 : __expf(o1) - 1.f;
    o2 = o2 > 0.f ? o2 : __expf(o2) - 1.f;
    o3 = o3 > 0.f ? o3 : __expf(o3) - 1.f;
    uint2 ov;
    ov.x = (unsigned)f2bf(o0) | ((unsigned)f2bf(o1) << 16);
    ov.y = (unsigned)f2bf(o2) | ((unsigned)f2bf(o3) << 16);
    *(uint2*)(h2b + (size_t)n * C1 + lane * 4) = ov;
}

// h3 = h2 @ W2 via MFMA bf16; h3 stored bf16; fused layer-2 attention dots
__global__ __launch_bounds__(256) void gemm2_mfma(const unsigned short* __restrict__ h2b,
                                                  const unsigned short* __restrict__ w2t,
                                                  const float* __restrict__ att_src,
                                                  const float* __restrict__ att_dst,
                                                  unsigned short* __restrict__ h3b,
                                                  float* __restrict__ a_src,
                                                  float* __restrict__ a_dst) {
    const int tid = threadIdx.x;
    const int w = tid >> 6, lane = tid & 63;
    const int l15 = lane & 15, kg = lane >> 4;
    const int mb = blockIdx.x * 64 + w * 16;
    int ar = mb + l15; if (ar >= NN) ar = NN - 1;

    short8v a[8];
    #pragma unroll
    for (int ks = 0; ks < 8; ++ks)
        a[ks] = *(const short8v*)(h2b + (size_t)ar * C1 + ks * 32 + kg * 8);

    short8v b[8][2];
    #pragma unroll
    for (int nt = 0; nt < 2; ++nt) {
        int nc = nt * 16 + l15;
        #pragma unroll
        for (int ks = 0; ks < 8; ++ks)
            b[ks][nt] = *(const short8v*)(w2t + (size_t)nc * C1 + ks * 32 + kg * 8);
    }

    floatx4 acc[2] = {{0.f,0.f,0.f,0.f},{0.f,0.f,0.f,0.f}};
    #pragma unroll
    for (int ks = 0; ks < 8; ++ks)
        #pragma unroll
        for (int nt = 0; nt < 2; ++nt)
            acc[nt] = __builtin_amdgcn_mfma_f32_16x16x32_bf16(a[ks], b[ks][nt], acc[nt], 0, 0, 0);

    #pragma unroll
    for (int nt = 0; nt < 2; ++nt)
        #pragma unroll
        for (int j = 0; j < 4; ++j) {
            int r = mb + kg * 4 + j;
            if (r < NN) h3b[(size_t)r * OUTC + nt * 16 + l15] = f2bf(acc[nt][j]);
        }

    float ws0 = att_src[l15], ws1 = att_src[16 + l15];
    float wd0 = att_dst[l15], wd1 = att_dst[16 + l15];
    #pragma unroll
    for (int j = 0; j < 4; ++j) {
        float ps = acc[0][j] * ws0 + acc[1][j] * ws1;
        float pd = acc[0][j] * wd0 + acc[1][j] * wd1;
        #pragma unroll
        for (int m = 8; m; m >>= 1) {
            ps += __shfl_xor(ps, m);
            pd += __shfl_xor(pd, m);
        }
        int r = mb + kg * 4 + j;
        if (l15 == 0 && r < NN) {
            a_src[r] = ps;
            a_dst[r] = pd;
        }
    }
}

// layer-2 aggregation, 4x unrolled, slot CSR (bf16 h3); analytic self-loop; padded curs
__global__ __launch_bounds__(256) void node2(const unsigned short* __restrict__ h3b,
                                             const int* __restrict__ curs,
                                             const int* __restrict__ slots,
                                             const float* __restrict__ a_src,
                                             const float* __restrict__ a_dst,
                                             const float* __restrict__ b2,
                                             float* __restrict__ out) {
    int wave = threadIdx.x >> 6, lane = threadIdx.x & 63;
    int half = lane >> 5, c = lane & 31;
    int n = blockIdx.x * 8 + wave * 2 + half;
    if (n >= NN) return;
    int cnt = curs[n * CSTRIDE]; if (cnt > SLOT_CAP) cnt = SLOT_CAP;
    const int* sl = slots + (size_t)n * SLOT_CAP;
    float adn = a_dst[n];
    float acc = 0.f, den = 0.f;
    {   // self-loop
        float e = __expf(lrelu(a_src[n] + adn));
        den += e;
        acc += bf2f(h3b[(size_t)n * OUTC + c]) * e;
    }
    int p = 0;
    for (; p + 3 < cnt; p += 4) {
        int s0 = sl[p], s1 = sl[p + 1], s2 = sl[p + 2], s3 = sl[p + 3];
        float g0 = bf2f(h3b[(size_t)s0 * OUTC + c]);
        float g1 = bf2f(h3b[(size_t)s1 * OUTC + c]);
        float g2 = bf2f(h3b[(size_t)s2 * OUTC + c]);
        float g3 = bf2f(h3b[(size_t)s3 * OUTC + c]);
        float e0 = __expf(lrelu(a_src[s0] + adn));
        float e1 = __expf(lrelu(a_src[s1] + adn));
        float e2 = __expf(lrelu(a_src[s2] + adn));
        float e3 = __expf(lrelu(a_src[s3] + adn));
        den += e0 + e1 + e2 + e3;
        acc += g0 * e0 + g1 * e1 + g2 * e2 + g3 * e3;
    }
    for (; p < cnt; ++p) {
        int s = sl[p];
        float e = __expf(lrelu(a_src[s] + adn));
        den += e;
        acc += bf2f(h3b[(size_t)s * OUTC + c]) * e;
    }
    out[(size_t)n * OUTC + c] = acc / (den + EPSV) + b2[c];
}

extern "C" void kernel_launch(void* const* d_in, const int* in_sizes, int n_in,
                              void* d_out, int out_size, void* d_ws, size_t ws_size,
                              hipStream_t stream) {
    if (ws_size < WS_NEED_FLOATS * 4ull) return;

    const float* x        = (const float*)d_in[0];
    const int* ei         = (const int*)d_in[1];
    const float* W1       = (const float*)d_in[2];
    const float* att_src1 = (const float*)d_in[3];
    const float* att_dst1 = (const float*)d_in[4];
    const float* b1       = (const float*)d_in[5];
    const float* W2       = (const float*)d_in[6];
    const float* att_src2 = (const float*)d_in[7];
    const float* att_dst2 = (const float*)d_in[8];
    const float* b2       = (const float*)d_in[9];
    float* out = (float*)d_out;
    float* ws  = (float*)d_ws;
    int*   wsi = (int*)d_ws;

    int*   curs   = wsi + CURS;
    float* a_src1 = ws + ASRC1;
    float* a_dst1 = ws + ADST1;
    float* a_src2 = ws + ASRC2;
    float* a_dst2 = ws + ADST2;
    int*   slots  = wsi + SLOTS;
    unsigned short* w1t = (unsigned short*)(ws + W1T);
    unsigned short* w2t = (unsigned short*)(ws + W2T);
    unsigned short* xbf = (unsigned short*)(ws + XBF);
    unsigned short* h1b = (unsigned short*)(ws + H1B);
    unsigned short* h2b = (unsigned short*)(ws + H2B);
    unsigned short* h3b = (unsigned short*)(ws + H3OFF);

    hipLaunchKernelGGL(prep, dim3(NB_PREP), dim3(256), 0, stream,
                       x, W1, W2, xbf, w1t, w2t, curs);
    hipLaunchKernelGGL(gemm1_scatter, dim3(NB_GS), dim3(256), 0, stream,
                       xbf, w1t, att_src1, att_dst1, ei, h1b, a_src1, a_dst1, curs, slots);
    hipLaunchKernelGGL(node1, dim3((NN + 3) / 4), dim3(256), 0, stream,
                       h1b, curs, slots, a_src1, a_dst1, b1, h2b);
    hipLaunchKernelGGL(gemm2_mfma, dim3((NN + 63) / 64), dim3(256), 0, stream,
                       h2b, w2t, att_src2, att_dst2, h3b, a_src2, a_dst2);
    hipLaunchKernelGGL(node2, dim3((NN + 7) / 8), dim3(256), 0, stream,
                       h3b, curs, slots, a_src2, a_dst2, b2, out);
}